// Round 3
// baseline (451.367 us; speedup 1.0000x reference)
//
#include <hip/hip_runtime.h>
#include <math.h>

constexpr int NN   = 100000;
constexpr int NE   = 1600000;
constexpr int FIN  = 256;
constexpr int HID  = 64;
constexpr int FOUT = 40;
constexpr float SLOPE = 0.2f;
constexpr int NB    = (NN + 255) / 256;   // 391 buckets (256 nodes/bucket)
constexpr int NBUCK = NB;
constexpr int TILE_A = 2048;              // edges per partition-A workgroup
constexpr int NWG_A = (NE + TILE_A - 1) / TILE_A;  // 782
constexpr int AK = 264;                   // LDS row stride in bf16 (256 + 8 pad)

typedef short  short8  __attribute__((ext_vector_type(8)));
typedef float  floatx4 __attribute__((ext_vector_type(4)));

__device__ inline unsigned short f2bf(float x) {   // RNE fp32->bf16
    union { float f; unsigned int u; } c; c.f = x;
    unsigned int u = c.u;
    return (unsigned short)((u + 0x7FFF + ((u >> 16) & 1)) >> 16);
}

__device__ inline float readlane_f(float v, int l) {
    return __int_as_float(__builtin_amdgcn_readlane(__float_as_int(v), l));
}

// ---------------- W1^T bf16 prep (once per launch) --------------------------
__global__ __launch_bounds__(256) void w1t_kernel(
    const float* __restrict__ W1, unsigned short* __restrict__ W1T)
{
    int idx = blockIdx.x * 256 + threadIdx.x;       // 16384 elems
    if (idx < FIN * HID) {
        int k = idx >> 6, n = idx & 63;
        W1T[n * FIN + k] = f2bf(W1[idx]);
    }
}

// ---------------- GEMM1 via bf16 MFMA: z = feat @ W1, fused el/er -----------
// A loaded DIRECTLY global->reg (coalesced 128B/row segments), converted to
// bf16 in registers. Only W1^T staged in LDS (~34 KB) -> 4 blocks/CU.
// Fused: LDS bucket histogram of dst>>8 merged into global bcnt[NBUCK].
// z stored as fp16 (halves gather-side traffic and footprint).
__global__ __launch_bounds__(256) void gemm1_kernel(
    const float* __restrict__ feat, const unsigned short* __restrict__ W1T,
    const float* __restrict__ al, const float* __restrict__ ar,
    const int* __restrict__ dst, int* __restrict__ bcnt,
    _Float16* __restrict__ z, float* __restrict__ el, float* __restrict__ er)
{
    __shared__ unsigned short sBT[64 * AK];   // W1^T bf16 [n][k]
    __shared__ int hist[NBUCK];
    const int t = threadIdx.x;
    const int ntile = blockIdx.x * 64;

    for (int i = t; i < NBUCK; i += 256) hist[i] = 0;
    // stage B^T: 2048 8-bf16 granules, 8 per thread
    #pragma unroll
    for (int i = 0; i < 8; ++i) {
        int g = t + 256 * i;
        int row = g >> 5, c8 = g & 31;
        *(uint4*)&sBT[row * AK + 8 * c8] = *(const uint4*)&W1T[row * FIN + 8 * c8];
    }
    __syncthreads();

    // bucket histogram: 1563 blocks * 256 thr * 4 edges >= NE
    {
        int base = (blockIdx.x * 256 + t) * 4;
        if (base < NE) {  // NE % 4 == 0
            const int4 d4 = *(const int4*)&dst[base];
            atomicAdd(&hist[d4.x >> 8], 1); atomicAdd(&hist[d4.y >> 8], 1);
            atomicAdd(&hist[d4.z >> 8], 1); atomicAdd(&hist[d4.w >> 8], 1);
        }
    }
    __syncthreads();
    for (int i = t; i < NBUCK; i += 256) {
        int hv = hist[i];
        if (hv) atomicAdd(&bcnt[i], hv);
    }

    const int w  = t >> 6;        // wave id -> node rows m0..m0+15
    const int l  = t & 63;
    const int lr = l & 15;        // A row / B col / D col within tile
    const int q  = l >> 4;        // quad
    const int m0 = 16 * w;

    int n = ntile + m0 + lr; if (n >= NN) n = NN - 1;
    const float* __restrict__ arow = feat + (size_t)n * FIN;

    floatx4 acc[4];
    #pragma unroll
    for (int tile = 0; tile < 4; ++tile) acc[tile] = 0.f;

    #pragma unroll
    for (int kc = 0; kc < 8; ++kc) {
        const int koff = kc * 32 + 8 * q;
        const float4 fa = *(const float4*)(arow + koff);
        const float4 fb = *(const float4*)(arow + koff + 4);
        short8 av;
        av[0] = (short)f2bf(fa.x); av[1] = (short)f2bf(fa.y);
        av[2] = (short)f2bf(fa.z); av[3] = (short)f2bf(fa.w);
        av[4] = (short)f2bf(fb.x); av[5] = (short)f2bf(fb.y);
        av[6] = (short)f2bf(fb.z); av[7] = (short)f2bf(fb.w);
        #pragma unroll
        for (int tile = 0; tile < 4; ++tile) {
            const short8 bv = *(const short8*)(sBT + (16 * tile + lr) * AK + koff);
            acc[tile] = __builtin_amdgcn_mfma_f32_16x16x32_bf16(av, bv, acc[tile], 0, 0, 0);
        }
    }

    // epilogue: z store (fp16) + el/er (reduce over n within 16-lane groups)
    float aln[4], arn[4];
    #pragma unroll
    for (int tile = 0; tile < 4; ++tile) {
        aln[tile] = al[16 * tile + lr];
        arn[tile] = ar[16 * tile + lr];
    }
    #pragma unroll
    for (int r = 0; r < 4; ++r) {
        int mg = ntile + m0 + 4 * q + r;
        float pl = 0.f, pr = 0.f;
        #pragma unroll
        for (int tile = 0; tile < 4; ++tile) {
            float zv = acc[tile][r];
            pl += zv * aln[tile]; pr += zv * arn[tile];
        }
        #pragma unroll
        for (int off = 8; off >= 1; off >>= 1) {
            pl += __shfl_xor(pl, off);
            pr += __shfl_xor(pr, off);
        }
        if (mg < NN) {
            #pragma unroll
            for (int tile = 0; tile < 4; ++tile)
                z[(size_t)mg * HID + 16 * tile + lr] = (_Float16)acc[tile][r];
            if (lr == 0) { el[mg] = pl; er[mg] = pr; }
        }
    }
}

// ---------------- GEMM2: z2 = h @ W2, fused el2/er2 (fp32 acc, fp16 store) --
__global__ __launch_bounds__(256) void gemm2_kernel(
    const float* __restrict__ h, const float* __restrict__ W2,
    const float* __restrict__ al, const float* __restrict__ ar,
    _Float16* __restrict__ z2, float* __restrict__ el, float* __restrict__ er)
{
    __shared__ float sh[4][64];
    const int w = threadIdx.x >> 6, lane = threadIdx.x & 63;
    const int n = blockIdx.x * 4 + w;          // NN % 4 == 0
    sh[w][lane] = h[(size_t)n * HID + lane];
    __syncthreads();
    float acc = 0.f;
    if (lane < FOUT) {
        #pragma unroll 8
        for (int k = 0; k < 64; ++k) acc += sh[w][k] * W2[k * FOUT + lane];
    }
    float pl = (lane < FOUT) ? acc * al[lane] : 0.f;
    float pr = (lane < FOUT) ? acc * ar[lane] : 0.f;
    #pragma unroll
    for (int off = 32; off >= 1; off >>= 1) { pl += __shfl_xor(pl, off); pr += __shfl_xor(pr, off); }
    if (lane == 0) { el[n] = pl; er[n] = pr; }
    if (lane < FOUT) z2[(size_t)n * FOUT + lane] = (_Float16)acc;
}

// ---------------- bucket scan (391 elems): bofs/gcur init -------------------
__global__ __launch_bounds__(512) void scan_top_kernel(
    const int* __restrict__ bcnt, int* __restrict__ bofs, int* __restrict__ gcur)
{
    __shared__ int tmp[512];
    int t = threadIdx.x;
    int v = (t < NB) ? bcnt[t] : 0;
    tmp[t] = v; __syncthreads();
    for (int off = 1; off < 512; off <<= 1) {
        int x = (t >= off) ? tmp[t - off] : 0;
        __syncthreads();
        tmp[t] += x;
        __syncthreads();
    }
    int excl = tmp[t] - v;
    if (t < NB) { bofs[t] = excl; gcur[t] = excl; }
    if (t == NB - 1) bofs[NB] = excl + v;  // == NE
}

// ---------------- Pass A: bucket partition (line-dense writes) --------------
// pack = (src << 8) | (dst & 255); bucket = dst >> 8
__global__ __launch_bounds__(256) void partitionA_kernel(
    const int* __restrict__ src, const int* __restrict__ dst,
    int* __restrict__ gcur, int* __restrict__ ebuck)
{
    __shared__ int hist[NBUCK];
    __shared__ int lcur[NBUCK];
    const int t = threadIdx.x;
    const int e0 = blockIdx.x * TILE_A;
    const int e1 = (e0 + TILE_A < NE) ? e0 + TILE_A : NE;

    for (int i = t; i < NBUCK; i += 256) hist[i] = 0;
    __syncthreads();
    for (int e = e0 + t; e < e1; e += 256)
        atomicAdd(&hist[dst[e] >> 8], 1);
    __syncthreads();
    for (int i = t; i < NBUCK; i += 256) {
        int hv = hist[i];
        lcur[i] = hv ? atomicAdd(&gcur[i], hv) : 0;
    }
    __syncthreads();
    for (int e = e0 + t; e < e1; e += 256) {
        int d = dst[e], s = src[e];
        int p = atomicAdd(&lcur[d >> 8], 1);
        ebuck[p] = (s << 8) | (d & 255);
    }
}

// ---------------- Pass B: per-bucket degree count + scan + CSR scatter ------
__global__ __launch_bounds__(256) void partitionB_kernel(
    const int* __restrict__ bofs, const int* __restrict__ ebuck,
    int* __restrict__ row_ptr, int* __restrict__ esrc)
{
    __shared__ int sdeg[256];
    __shared__ int sscan[256];
    const int b = blockIdx.x;
    const int n0 = b << 8;
    const int t = threadIdx.x;
    const int r0 = bofs[b], r1 = bofs[b + 1];

    sdeg[t] = 0;
    __syncthreads();
    for (int e = r0 + t; e < r1; e += 256)
        atomicAdd(&sdeg[ebuck[e] & 255], 1);
    __syncthreads();

    // inclusive Hillis-Steele scan over 256 degrees
    int v = sdeg[t];
    sscan[t] = v;
    __syncthreads();
    for (int off = 1; off < 256; off <<= 1) {
        int x = (t >= off) ? sscan[t - off] : 0;
        __syncthreads();
        sscan[t] += x;
        __syncthreads();
    }
    int excl = sscan[t] - v;
    if (n0 + t < NN) row_ptr[n0 + t] = r0 + excl;
    if (b == NBUCK - 1 && t == 0) row_ptr[NN] = NE;

    sdeg[t] = r0 + excl;     // cursor (each thread owns its own slot)
    __syncthreads();
    for (int e = r0 + t; e < r1; e += 256) {
        int pk = ebuck[e];
        int p = atomicAdd(&sdeg[pk & 255], 1);
        esrc[p] = pk >> 8;
    }
}

// ---------------- fused per-destination GAT gather (fp16 z) ----------------
// Per-edge (weight, src) pairs are wave-uniform: broadcast via v_readlane into
// SGPRs so the z-row base address is SCALAR and the load is saddr+lane-offset.
template<int F, bool FINAL_LAYER>
__global__ __launch_bounds__(256) void gat_gather_kernel(
    const int* __restrict__ row_ptr, const int* __restrict__ esrc,
    const float* __restrict__ el, const float* __restrict__ er,
    const _Float16* __restrict__ z, const float* __restrict__ bias,
    float* __restrict__ out)
{
    const int w = threadIdx.x >> 6, lane = threadIdx.x & 63;
    const int d = blockIdx.x * 4 + w;          // NN % 4 == 0
    const int r0 = row_ptr[d], r1 = row_ptr[d + 1];
    const int cnt = r1 - r0;
    const float erd = er[d];

    float accv = 0.f;
    float s = 0.f;

    if (cnt <= 64) {
        int sn = 0; float v = -INFINITY;
        if (lane < cnt) {
            sn = esrc[r0 + lane];
            v = el[sn] + erd;
            v = (v >= 0.f) ? v : SLOPE * v;
        }
        float m = v;
        #pragma unroll
        for (int off = 32; off >= 1; off >>= 1) m = fmaxf(m, __shfl_xor(m, off));
        float wv = (lane < cnt) ? __expf(v - m) : 0.f;
        s = wv;
        #pragma unroll
        for (int off = 32; off >= 1; off >>= 1) s += __shfl_xor(s, off);
        if (lane < F) {
            int j = 0;
            for (; j + 8 <= cnt; j += 8) {
                float a0 = 0.f, a1 = 0.f;
                #pragma unroll
                for (int qq = 0; qq < 8; qq += 2) {
                    float w0 = readlane_f(wv, j + qq);
                    int   s0 = __builtin_amdgcn_readlane(sn, j + qq);
                    float w1 = readlane_f(wv, j + qq + 1);
                    int   s1 = __builtin_amdgcn_readlane(sn, j + qq + 1);
                    a0 += w0 * (float)z[(size_t)s0 * F + lane];
                    a1 += w1 * (float)z[(size_t)s1 * F + lane];
                }
                accv += a0 + a1;
            }
            for (; j < cnt; ++j) {
                float w0 = readlane_f(wv, j);
                int   s0 = __builtin_amdgcn_readlane(sn, j);
                accv += w0 * (float)z[(size_t)s0 * F + lane];
            }
        }
    } else {
        float m = -INFINITY;
        for (int e = r0 + lane; e < r1; e += 64) {
            float v = el[esrc[e]] + erd;
            v = (v >= 0.f) ? v : SLOPE * v;
            m = fmaxf(m, v);
        }
        #pragma unroll
        for (int off = 32; off >= 1; off >>= 1) m = fmaxf(m, __shfl_xor(m, off));
        for (int base = r0; base < r1; base += 64) {
            int e = base + lane;
            float wv = 0.f; int sn = 0;
            if (e < r1) {
                sn = esrc[e];
                float v = el[sn] + erd;
                v = (v >= 0.f) ? v : SLOPE * v;
                wv = __expf(v - m);
            }
            s += wv;
            int c = r1 - base; if (c > 64) c = 64;
            if (lane < F) {
                int j = 0;
                for (; j + 4 <= c; j += 4) {
                    float a0 = 0.f, a1 = 0.f;
                    #pragma unroll
                    for (int qq = 0; qq < 4; qq += 2) {
                        float w0 = readlane_f(wv, j + qq);
                        int   s0 = __builtin_amdgcn_readlane(sn, j + qq);
                        float w1 = readlane_f(wv, j + qq + 1);
                        int   s1 = __builtin_amdgcn_readlane(sn, j + qq + 1);
                        a0 += w0 * (float)z[(size_t)s0 * F + lane];
                        a1 += w1 * (float)z[(size_t)s1 * F + lane];
                    }
                    accv += a0 + a1;
                }
                for (; j < c; ++j) {
                    float w0 = readlane_f(wv, j);
                    int   s0 = __builtin_amdgcn_readlane(sn, j);
                    accv += w0 * (float)z[(size_t)s0 * F + lane];
                }
            }
        }
        #pragma unroll
        for (int off = 32; off >= 1; off >>= 1) s += __shfl_xor(s, off);
    }

    float res = (cnt > 0) ? (accv / s) : 0.f;

    if (!FINAL_LAYER) {
        if (lane < F) {
            float v = res + bias[lane];
            out[(size_t)d * F + lane] = (v > 0.f) ? v : 0.f;
        }
    } else {
        float v = (lane < F) ? res + bias[lane] : -INFINITY;
        float mx = v;
        #pragma unroll
        for (int off = 32; off >= 1; off >>= 1) mx = fmaxf(mx, __shfl_xor(mx, off));
        float ex = (lane < F) ? __expf(v - mx) : 0.f;
        float sm = ex;
        #pragma unroll
        for (int off = 32; off >= 1; off >>= 1) sm += __shfl_xor(sm, off);
        if (lane < F) out[(size_t)d * F + lane] = v - mx - __logf(sm);
    }
}

extern "C" void kernel_launch(void* const* d_in, const int* in_sizes, int n_in,
                              void* d_out, int out_size, void* d_ws, size_t ws_size,
                              hipStream_t stream) {
    const float* feat = (const float*)d_in[0];
    const int*   src  = (const int*)d_in[1];
    const int*   dst  = (const int*)d_in[2];
    const float* W1   = (const float*)d_in[3];
    const float* b1   = (const float*)d_in[4];
    const float* al1  = (const float*)d_in[5];
    const float* ar1  = (const float*)d_in[6];
    const float* W2   = (const float*)d_in[7];
    const float* b2   = (const float*)d_in[8];
    const float* al2  = (const float*)d_in[9];
    const float* ar2  = (const float*)d_in[10];
    float* out = (float*)d_out;

    float* ws    = (float*)d_ws;
    _Float16* z1 = (_Float16*)ws;               // NN*64 fp16 (reused for z2)
    float* h     = ws + (size_t)NN * HID / 2 + 64;  // NN*64 fp32 (z1 region is half-size)
    float* el1   = h + (size_t)NN * HID;
    float* er1   = el1 + NN;
    float* el2   = er1 + NN;
    float* er2   = el2 + NN;
    int*   bcnt  = (int*)(er2 + NN);            // NB
    int*   bofs  = bcnt + NB;                   // NB+1
    int*   gcur  = bofs + NB + 1;               // NBUCK
    int*   rowp  = gcur + NBUCK;                // NN+1
    int*   esrc  = rowp + NN + 1;               // NE
    unsigned short* w1t = (unsigned short*)(esrc + NE);  // FIN*HID bf16
    int*   ebuck = (int*)h;                     // NE ints, dead before gather1 writes h
    _Float16* z2 = z1;

    hipMemsetAsync(bcnt, 0, NB * sizeof(int), stream);

    // ---- W1^T bf16 prep + layer-1 MFMA GEMM with fused bucket histogram ----
    w1t_kernel<<<(FIN * HID + 255) / 256, 256, 0, stream>>>(W1, w1t);
    gemm1_kernel<<<(NN + 63) / 64, 256, 0, stream>>>(feat, w1t, al1, ar1, dst, bcnt, z1, el1, er1);

    // ---- CSR build (bucket scan -> partition -> per-bucket scan/scatter) ----
    scan_top_kernel<<<1, 512, 0, stream>>>(bcnt, bofs, gcur);
    partitionA_kernel<<<NWG_A, 256, 0, stream>>>(src, dst, gcur, ebuck);
    partitionB_kernel<<<NBUCK, 256, 0, stream>>>(bofs, ebuck, rowp, esrc);

    // ---- layer 1 gather ----
    gat_gather_kernel<HID, false><<<NN / 4, 256, 0, stream>>>(rowp, esrc, el1, er1, z1, b1, h);

    // ---- layer 2 ----
    gemm2_kernel<<<NN / 4, 256, 0, stream>>>(h, W2, al2, ar2, z2, el2, er2);
    gat_gather_kernel<FOUT, true><<<NN / 4, 256, 0, stream>>>(rowp, esrc, el2, er2, z2, b2, out);
}

// Round 4
// 414.033 us; speedup vs baseline: 1.0902x; 1.0902x over previous
//
#include <hip/hip_runtime.h>
#include <math.h>

constexpr int NN   = 100000;
constexpr int NE   = 1600000;
constexpr int FIN  = 256;
constexpr int HID  = 64;
constexpr int FOUT = 40;
constexpr float SLOPE = 0.2f;
constexpr int NB    = (NN + 255) / 256;   // 391 buckets (256 nodes/bucket)
constexpr int NBUCK = NB;
constexpr int TILE_A = 2048;              // edges per partition-A workgroup
constexpr int NWG_A = (NE + TILE_A - 1) / TILE_A;  // 782
constexpr int AK = 264;                   // LDS row stride in bf16 (256 + 8 pad)

typedef short  short8  __attribute__((ext_vector_type(8)));
typedef float  floatx4 __attribute__((ext_vector_type(4)));

__device__ inline unsigned short f2bf(float x) {   // RNE fp32->bf16
    union { float f; unsigned int u; } c; c.f = x;
    unsigned int u = c.u;
    return (unsigned short)((u + 0x7FFF + ((u >> 16) & 1)) >> 16);
}

__device__ inline float readlane_f(float v, int l) {
    return __int_as_float(__builtin_amdgcn_readlane(__float_as_int(v), l));
}

// ---------------- W1^T bf16 prep (once per launch) --------------------------
__global__ __launch_bounds__(256) void w1t_kernel(
    const float* __restrict__ W1, unsigned short* __restrict__ W1T)
{
    int idx = blockIdx.x * 256 + threadIdx.x;       // 16384 elems
    if (idx < FIN * HID) {
        int k = idx >> 6, n = idx & 63;
        W1T[n * FIN + k] = f2bf(W1[idx]);
    }
}

// ---------------- GEMM1 via bf16 MFMA: z = feat @ W1, fused el/er -----------
// A loaded DIRECTLY global->reg (coalesced 128B/row segments), converted to
// bf16 in registers. Only W1^T staged in LDS (~34 KB) -> 4 blocks/CU.
// Fused: LDS bucket histogram of dst>>8 merged into global bcnt[NBUCK].
// z stored as fp16 (halves gather-side traffic and footprint).
__global__ __launch_bounds__(256) void gemm1_kernel(
    const float* __restrict__ feat, const unsigned short* __restrict__ W1T,
    const float* __restrict__ al, const float* __restrict__ ar,
    const int* __restrict__ dst, int* __restrict__ bcnt,
    _Float16* __restrict__ z, float* __restrict__ el, float* __restrict__ er)
{
    __shared__ unsigned short sBT[64 * AK];   // W1^T bf16 [n][k]
    __shared__ int hist[NBUCK];
    const int t = threadIdx.x;
    const int ntile = blockIdx.x * 64;

    for (int i = t; i < NBUCK; i += 256) hist[i] = 0;
    // stage B^T: 2048 8-bf16 granules, 8 per thread
    #pragma unroll
    for (int i = 0; i < 8; ++i) {
        int g = t + 256 * i;
        int row = g >> 5, c8 = g & 31;
        *(uint4*)&sBT[row * AK + 8 * c8] = *(const uint4*)&W1T[row * FIN + 8 * c8];
    }
    __syncthreads();

    // bucket histogram: 1563 blocks * 256 thr * 4 edges == NE
    {
        int base = (blockIdx.x * 256 + t) * 4;
        if (base < NE) {  // NE % 4 == 0
            const int4 d4 = *(const int4*)&dst[base];
            atomicAdd(&hist[d4.x >> 8], 1); atomicAdd(&hist[d4.y >> 8], 1);
            atomicAdd(&hist[d4.z >> 8], 1); atomicAdd(&hist[d4.w >> 8], 1);
        }
    }
    __syncthreads();
    for (int i = t; i < NBUCK; i += 256) {
        int hv = hist[i];
        if (hv) atomicAdd(&bcnt[i], hv);
    }

    const int w  = t >> 6;        // wave id -> node rows m0..m0+15
    const int l  = t & 63;
    const int lr = l & 15;        // A row / B col / D col within tile
    const int q  = l >> 4;        // quad
    const int m0 = 16 * w;

    int n = ntile + m0 + lr; if (n >= NN) n = NN - 1;
    const float* __restrict__ arow = feat + (size_t)n * FIN;

    floatx4 acc[4];
    #pragma unroll
    for (int tile = 0; tile < 4; ++tile) acc[tile] = 0.f;

    #pragma unroll
    for (int kc = 0; kc < 8; ++kc) {
        const int koff = kc * 32 + 8 * q;
        const float4 fa = *(const float4*)(arow + koff);
        const float4 fb = *(const float4*)(arow + koff + 4);
        short8 av;
        av[0] = (short)f2bf(fa.x); av[1] = (short)f2bf(fa.y);
        av[2] = (short)f2bf(fa.z); av[3] = (short)f2bf(fa.w);
        av[4] = (short)f2bf(fb.x); av[5] = (short)f2bf(fb.y);
        av[6] = (short)f2bf(fb.z); av[7] = (short)f2bf(fb.w);
        #pragma unroll
        for (int tile = 0; tile < 4; ++tile) {
            const short8 bv = *(const short8*)(sBT + (16 * tile + lr) * AK + koff);
            acc[tile] = __builtin_amdgcn_mfma_f32_16x16x32_bf16(av, bv, acc[tile], 0, 0, 0);
        }
    }

    // epilogue: z store (fp16) + el/er (reduce over n within 16-lane groups)
    float aln[4], arn[4];
    #pragma unroll
    for (int tile = 0; tile < 4; ++tile) {
        aln[tile] = al[16 * tile + lr];
        arn[tile] = ar[16 * tile + lr];
    }
    #pragma unroll
    for (int r = 0; r < 4; ++r) {
        int mg = ntile + m0 + 4 * q + r;
        float pl = 0.f, pr = 0.f;
        #pragma unroll
        for (int tile = 0; tile < 4; ++tile) {
            float zv = acc[tile][r];
            pl += zv * aln[tile]; pr += zv * arn[tile];
        }
        #pragma unroll
        for (int off = 8; off >= 1; off >>= 1) {
            pl += __shfl_xor(pl, off);
            pr += __shfl_xor(pr, off);
        }
        if (mg < NN) {
            #pragma unroll
            for (int tile = 0; tile < 4; ++tile)
                z[(size_t)mg * HID + 16 * tile + lr] = (_Float16)acc[tile][r];
            if (lr == 0) { el[mg] = pl; er[mg] = pr; }
        }
    }
}

// ---------------- bucket scan (391 elems): bofs/gcur init -------------------
__global__ __launch_bounds__(512) void scan_top_kernel(
    const int* __restrict__ bcnt, int* __restrict__ bofs, int* __restrict__ gcur)
{
    __shared__ int tmp[512];
    int t = threadIdx.x;
    int v = (t < NB) ? bcnt[t] : 0;
    tmp[t] = v; __syncthreads();
    for (int off = 1; off < 512; off <<= 1) {
        int x = (t >= off) ? tmp[t - off] : 0;
        __syncthreads();
        tmp[t] += x;
        __syncthreads();
    }
    int excl = tmp[t] - v;
    if (t < NB) { bofs[t] = excl; gcur[t] = excl; }
    if (t == NB - 1) bofs[NB] = excl + v;  // == NE
}

// ---------------- Pass A: bucket partition (1024-thr blocks) ----------------
// pack = (src << 8) | (dst & 255); bucket = dst >> 8
__global__ __launch_bounds__(1024) void partitionA_kernel(
    const int* __restrict__ src, const int* __restrict__ dst,
    int* __restrict__ gcur, int* __restrict__ ebuck)
{
    __shared__ int hist[NBUCK];
    __shared__ int lcur[NBUCK];
    const int t = threadIdx.x;
    const int e0 = blockIdx.x * TILE_A;
    const int e1 = (e0 + TILE_A < NE) ? e0 + TILE_A : NE;

    for (int i = t; i < NBUCK; i += 1024) hist[i] = 0;
    __syncthreads();
    for (int e = e0 + t; e < e1; e += 1024)
        atomicAdd(&hist[dst[e] >> 8], 1);
    __syncthreads();
    for (int i = t; i < NBUCK; i += 1024) {
        int hv = hist[i];
        lcur[i] = hv ? atomicAdd(&gcur[i], hv) : 0;
    }
    __syncthreads();
    for (int e = e0 + t; e < e1; e += 1024) {
        int d = dst[e], s = src[e];
        int p = atomicAdd(&lcur[d >> 8], 1);
        ebuck[p] = (s << 8) | (d & 255);
    }
}

// ---------------- Pass B: per-bucket degree count + scan + CSR scatter ------
// 1024-thread blocks (was 256): 391 blocks x 16 waves ~ 6 waves/SIMD.
__global__ __launch_bounds__(1024) void partitionB_kernel(
    const int* __restrict__ bofs, const int* __restrict__ ebuck,
    int* __restrict__ row_ptr, int* __restrict__ esrc)
{
    __shared__ int sdeg[256];
    __shared__ int sscan[256];
    __shared__ int scur[256];
    const int b = blockIdx.x;
    const int n0 = b << 8;
    const int t = threadIdx.x;
    const int r0 = bofs[b], r1 = bofs[b + 1];

    if (t < 256) sdeg[t] = 0;
    __syncthreads();
    for (int e = r0 + t; e < r1; e += 1024)
        atomicAdd(&sdeg[ebuck[e] & 255], 1);
    __syncthreads();

    // inclusive Hillis-Steele scan over 256 degrees (threads 0..255)
    if (t < 256) sscan[t] = sdeg[t];
    __syncthreads();
    for (int off = 1; off < 256; off <<= 1) {
        int x = 0;
        if (t < 256 && t >= off) x = sscan[t - off];
        __syncthreads();
        if (t < 256) sscan[t] += x;
        __syncthreads();
    }
    if (t < 256) {
        int excl = sscan[t] - sdeg[t];
        if (n0 + t < NN) row_ptr[n0 + t] = r0 + excl;
        scur[t] = r0 + excl;
    }
    if (b == NBUCK - 1 && t == 0) row_ptr[NN] = NE;
    __syncthreads();

    for (int e = r0 + t; e < r1; e += 1024) {
        int pk = ebuck[e];
        int p = atomicAdd(&scur[pk & 255], 1);
        esrc[p] = pk >> 8;
    }
}

// ---------------- fused per-destination GAT gather (fp16 z) ----------------
// Per-edge (weight, src) pairs are wave-uniform: broadcast via v_readlane into
// SGPRs so the z-row base address is SCALAR and the load is saddr+lane-offset.
// !FINAL variant fuses GEMM2 (z2 = relu(res+b1) @ W2) + el2/er2 into the
// epilogue: h never touches global memory. W2 staged in LDS once per block.
template<int F, bool FINAL_LAYER>
__global__ __launch_bounds__(256) void gat_gather_kernel(
    const int* __restrict__ row_ptr, const int* __restrict__ esrc,
    const float* __restrict__ el, const float* __restrict__ er,
    const _Float16* __restrict__ z, const float* __restrict__ bias,
    const float* __restrict__ W2, const float* __restrict__ al2,
    const float* __restrict__ ar2,
    _Float16* __restrict__ z2, float* __restrict__ el2, float* __restrict__ er2,
    float* __restrict__ out)
{
    __shared__ float sW2[HID * FOUT];   // 10 KB (only used when !FINAL)
    __shared__ float sh[4][HID];        // 1 KB per-wave h row (only !FINAL)
    const int w = threadIdx.x >> 6, lane = threadIdx.x & 63;
    const int d = blockIdx.x * 4 + w;          // NN % 4 == 0
    const int r0 = row_ptr[d], r1 = row_ptr[d + 1];
    const int cnt = r1 - r0;
    const float erd = er[d];

    if (!FINAL_LAYER) {
        for (int i = threadIdx.x; i < HID * FOUT; i += 256) sW2[i] = W2[i];
        __syncthreads();
    }

    float accv = 0.f;
    float s = 0.f;

    if (cnt <= 64) {
        int sn = 0; float v = -INFINITY;
        if (lane < cnt) {
            sn = esrc[r0 + lane];
            v = el[sn] + erd;
            v = (v >= 0.f) ? v : SLOPE * v;
        }
        float m = v;
        #pragma unroll
        for (int off = 32; off >= 1; off >>= 1) m = fmaxf(m, __shfl_xor(m, off));
        float wv = (lane < cnt) ? __expf(v - m) : 0.f;
        s = wv;
        #pragma unroll
        for (int off = 32; off >= 1; off >>= 1) s += __shfl_xor(s, off);
        if (lane < F) {
            int j = 0;
            for (; j + 8 <= cnt; j += 8) {
                float a0 = 0.f, a1 = 0.f;
                #pragma unroll
                for (int qq = 0; qq < 8; qq += 2) {
                    float w0 = readlane_f(wv, j + qq);
                    int   s0 = __builtin_amdgcn_readlane(sn, j + qq);
                    float w1 = readlane_f(wv, j + qq + 1);
                    int   s1 = __builtin_amdgcn_readlane(sn, j + qq + 1);
                    a0 += w0 * (float)z[(size_t)s0 * F + lane];
                    a1 += w1 * (float)z[(size_t)s1 * F + lane];
                }
                accv += a0 + a1;
            }
            for (; j < cnt; ++j) {
                float w0 = readlane_f(wv, j);
                int   s0 = __builtin_amdgcn_readlane(sn, j);
                accv += w0 * (float)z[(size_t)s0 * F + lane];
            }
        }
    } else {
        float m = -INFINITY;
        for (int e = r0 + lane; e < r1; e += 64) {
            float v = el[esrc[e]] + erd;
            v = (v >= 0.f) ? v : SLOPE * v;
            m = fmaxf(m, v);
        }
        #pragma unroll
        for (int off = 32; off >= 1; off >>= 1) m = fmaxf(m, __shfl_xor(m, off));
        for (int base = r0; base < r1; base += 64) {
            int e = base + lane;
            float wv = 0.f; int sn = 0;
            if (e < r1) {
                sn = esrc[e];
                float v = el[sn] + erd;
                v = (v >= 0.f) ? v : SLOPE * v;
                wv = __expf(v - m);
            }
            s += wv;
            int c = r1 - base; if (c > 64) c = 64;
            if (lane < F) {
                int j = 0;
                for (; j + 4 <= c; j += 4) {
                    float a0 = 0.f, a1 = 0.f;
                    #pragma unroll
                    for (int qq = 0; qq < 4; qq += 2) {
                        float w0 = readlane_f(wv, j + qq);
                        int   s0 = __builtin_amdgcn_readlane(sn, j + qq);
                        float w1 = readlane_f(wv, j + qq + 1);
                        int   s1 = __builtin_amdgcn_readlane(sn, j + qq + 1);
                        a0 += w0 * (float)z[(size_t)s0 * F + lane];
                        a1 += w1 * (float)z[(size_t)s1 * F + lane];
                    }
                    accv += a0 + a1;
                }
                for (; j < c; ++j) {
                    float w0 = readlane_f(wv, j);
                    int   s0 = __builtin_amdgcn_readlane(sn, j);
                    accv += w0 * (float)z[(size_t)s0 * F + lane];
                }
            }
        }
        #pragma unroll
        for (int off = 32; off >= 1; off >>= 1) s += __shfl_xor(s, off);
    }

    float res = (cnt > 0) ? (accv / s) : 0.f;

    if (!FINAL_LAYER) {
        // h = relu(res + b1) lives in lanes; fused GEMM2 + el2/er2 in-wave.
        float hval = res + bias[lane];          // F == HID == 64: all lanes
        hval = (hval > 0.f) ? hval : 0.f;
        sh[w][lane] = hval;                     // wave-synchronous LDS
        float acc2 = 0.f;
        if (lane < FOUT) {
            #pragma unroll 8
            for (int k = 0; k < HID; ++k) acc2 += sh[w][k] * sW2[k * FOUT + lane];
        }
        float pl = (lane < FOUT) ? acc2 * al2[lane] : 0.f;
        float pr = (lane < FOUT) ? acc2 * ar2[lane] : 0.f;
        #pragma unroll
        for (int off = 32; off >= 1; off >>= 1) {
            pl += __shfl_xor(pl, off); pr += __shfl_xor(pr, off);
        }
        if (lane == 0) { el2[d] = pl; er2[d] = pr; }
        if (lane < FOUT) z2[(size_t)d * FOUT + lane] = (_Float16)acc2;
    } else {
        float v = (lane < F) ? res + bias[lane] : -INFINITY;
        float mx = v;
        #pragma unroll
        for (int off = 32; off >= 1; off >>= 1) mx = fmaxf(mx, __shfl_xor(mx, off));
        float ex = (lane < F) ? __expf(v - mx) : 0.f;
        float sm = ex;
        #pragma unroll
        for (int off = 32; off >= 1; off >>= 1) sm += __shfl_xor(sm, off);
        if (lane < F) out[(size_t)d * F + lane] = v - mx - __logf(sm);
    }
}

extern "C" void kernel_launch(void* const* d_in, const int* in_sizes, int n_in,
                              void* d_out, int out_size, void* d_ws, size_t ws_size,
                              hipStream_t stream) {
    const float* feat = (const float*)d_in[0];
    const int*   src  = (const int*)d_in[1];
    const int*   dst  = (const int*)d_in[2];
    const float* W1   = (const float*)d_in[3];
    const float* b1   = (const float*)d_in[4];
    const float* al1  = (const float*)d_in[5];
    const float* ar1  = (const float*)d_in[6];
    const float* W2   = (const float*)d_in[7];
    const float* b2   = (const float*)d_in[8];
    const float* al2  = (const float*)d_in[9];
    const float* ar2  = (const float*)d_in[10];
    float* out = (float*)d_out;

    char* p = (char*)d_ws;
    _Float16* z1 = (_Float16*)p;  p += (size_t)NN * HID * 2;    // 12.8 MB
    _Float16* z2 = (_Float16*)p;  p += (size_t)NN * FOUT * 2;   // 8 MB
    float* el1   = (float*)p;     p += (size_t)NN * 4;
    float* er1   = (float*)p;     p += (size_t)NN * 4;
    float* el2   = (float*)p;     p += (size_t)NN * 4;
    float* er2   = (float*)p;     p += (size_t)NN * 4;
    int*   bcnt  = (int*)p;       p += NB * 4;
    int*   bofs  = (int*)p;       p += (NB + 1) * 4;
    int*   gcur  = (int*)p;       p += NBUCK * 4;
    int*   rowp  = (int*)p;       p += (NN + 1) * 4;
    int*   esrc  = (int*)p;       p += (size_t)NE * 4;          // 6.4 MB
    int*   ebuck = (int*)p;       p += (size_t)NE * 4;          // 6.4 MB
    unsigned short* w1t = (unsigned short*)p;                   // FIN*HID bf16

    hipMemsetAsync(bcnt, 0, NB * sizeof(int), stream);

    // ---- W1^T bf16 prep + layer-1 MFMA GEMM with fused bucket histogram ----
    w1t_kernel<<<(FIN * HID + 255) / 256, 256, 0, stream>>>(W1, w1t);
    gemm1_kernel<<<(NN + 63) / 64, 256, 0, stream>>>(feat, w1t, al1, ar1, dst, bcnt, z1, el1, er1);

    // ---- CSR build (bucket scan -> partition -> per-bucket scan/scatter) ----
    scan_top_kernel<<<1, 512, 0, stream>>>(bcnt, bofs, gcur);
    partitionA_kernel<<<NWG_A, 1024, 0, stream>>>(src, dst, gcur, ebuck);
    partitionB_kernel<<<NBUCK, 1024, 0, stream>>>(bofs, ebuck, rowp, esrc);

    // ---- layer-1 gather with fused GEMM2 (emits z2, el2, er2; h never stored)
    gat_gather_kernel<HID, false><<<NN / 4, 256, 0, stream>>>(
        rowp, esrc, el1, er1, z1, b1, W2, al2, ar2, z2, el2, er2, nullptr);

    // ---- layer-2 gather + log_softmax ----
    gat_gather_kernel<FOUT, true><<<NN / 4, 256, 0, stream>>>(
        rowp, esrc, el2, er2, z2, b2, nullptr, nullptr, nullptr,
        nullptr, nullptr, nullptr, out);
}